// Round 1
// baseline (59.319 us; speedup 1.0000x reference)
//
#include <hip/hip_runtime.h>
#include <math.h>

// Siddon exact forward projector, incremental traversal.
// Matches the JAX reference: merged sorted plane crossings in (t_min,t_max),
// per-segment midpoint voxel lookup, sum(dt*val) * ||dst-src||.

constexpr int   NV    = 128;
constexpr float EPS_F = 1e-12f;
constexpr float BIG_F = 1e9f;

__global__ __launch_bounds__(256)
void siddon_fwd_kernel(const float* __restrict__ vol,
                       const float* __restrict__ Mptr,
                       const float* __restrict__ bptr,
                       const float* __restrict__ src,
                       const float* __restrict__ dst,
                       float* __restrict__ out,
                       int n_ray)
{
    int r = blockIdx.x * blockDim.x + threadIdx.x;
    if (r >= n_ray) return;

    // ---- uniform: M inverse via adjugate (M is tiny; per-thread is cheap) ----
    float m00 = Mptr[0], m01 = Mptr[1], m02 = Mptr[2];
    float m10 = Mptr[3], m11 = Mptr[4], m12 = Mptr[5];
    float m20 = Mptr[6], m21 = Mptr[7], m22 = Mptr[8];
    float det = m00*(m11*m22 - m12*m21) - m01*(m10*m22 - m12*m20)
              + m02*(m10*m21 - m11*m20);
    float idet = 1.0f / det;
    float i00 =  (m11*m22 - m12*m21)*idet;
    float i01 = -(m01*m22 - m02*m21)*idet;
    float i02 =  (m01*m12 - m02*m11)*idet;
    float i10 = -(m10*m22 - m12*m20)*idet;
    float i11 =  (m00*m22 - m02*m20)*idet;
    float i12 = -(m00*m12 - m02*m10)*idet;
    float i20 =  (m10*m21 - m11*m20)*idet;
    float i21 = -(m00*m21 - m01*m20)*idet;
    float i22 =  (m00*m11 - m01*m10)*idet;

    float bx = bptr[0], by = bptr[1], bz = bptr[2];

    float sxw = src[3*r+0], syw = src[3*r+1], szw = src[3*r+2];
    float exw = dst[3*r+0], eyw = dst[3*r+1], ezw = dst[3*r+2];

    float wx = exw - sxw, wy = eyw - syw, wz = ezw - szw;
    float ray_len = sqrtf(wx*wx + wy*wy + wz*wz);

    // endpoints in voxel-index coords: p = Minv @ (world - b)
    float ux = sxw - bx, uy = syw - by, uz = szw - bz;
    float p0x = i00*ux + i01*uy + i02*uz;
    float p0y = i10*ux + i11*uy + i12*uz;
    float p0z = i20*ux + i21*uy + i22*uz;
    float vx = exw - bx, vy = eyw - by, vz = ezw - bz;
    float p1x = i00*vx + i01*vy + i02*vz;
    float p1y = i10*vx + i11*vy + i12*vz;
    float p1z = i20*vx + i21*vy + i22*vz;

    float dx = p1x - p0x, dy = p1y - p0y, dz = p1z - p0z;

    bool parx = fabsf(dx) < EPS_F;
    bool pary = fabsf(dy) < EPS_F;
    bool parz = fabsf(dz) < EPS_F;

    // ---- slab intersection (matches reference parallel-axis semantics) ----
    float tmin = 0.0f, tmax = 1.0f;
    {
        if (parx) {
            bool inside = (p0x >= 0.0f) && (p0x <= (float)NV);
            tmin = fmaxf(tmin, inside ? 0.0f : BIG_F);
            tmax = fminf(tmax, inside ? 1.0f : -BIG_F);
        } else {
            float t0 = (0.0f - p0x) / dx;
            float t1 = ((float)NV - p0x) / dx;
            tmin = fmaxf(tmin, fminf(t0, t1));
            tmax = fminf(tmax, fmaxf(t0, t1));
        }
        if (pary) {
            bool inside = (p0y >= 0.0f) && (p0y <= (float)NV);
            tmin = fmaxf(tmin, inside ? 0.0f : BIG_F);
            tmax = fminf(tmax, inside ? 1.0f : -BIG_F);
        } else {
            float t0 = (0.0f - p0y) / dy;
            float t1 = ((float)NV - p0y) / dy;
            tmin = fmaxf(tmin, fminf(t0, t1));
            tmax = fminf(tmax, fmaxf(t0, t1));
        }
        if (parz) {
            bool inside = (p0z >= 0.0f) && (p0z <= (float)NV);
            tmin = fmaxf(tmin, inside ? 0.0f : BIG_F);
            tmax = fminf(tmax, inside ? 1.0f : -BIG_F);
        } else {
            float t0 = (0.0f - p0z) / dz;
            float t1 = ((float)NV - p0z) / dz;
            tmin = fmaxf(tmin, fminf(t0, t1));
            tmax = fminf(tmax, fmaxf(t0, t1));
        }
    }

    if (!(tmax > tmin)) { out[r] = 0.0f; return; }

    // ---- incremental traversal init: next crossing t per axis ----
    float tx = BIG_F, ty = BIG_F, tz = BIG_F;
    float invx = 0.0f, invy = 0.0f, invz = 0.0f;
    int plx = 0, ply = 0, plz = 0;
    int stx = 0, sty = 0, stz = 0;

    if (!parx) {
        invx = 1.0f / dx;
        float q = p0x + tmin * dx;
        if (dx > 0.0f) { stx = 1;  plx = (int)floorf(q) + 1; }
        else           { stx = -1; plx = (int)ceilf(q)  - 1; }
        tx = ((float)plx - p0x) * invx;
    }
    if (!pary) {
        invy = 1.0f / dy;
        float q = p0y + tmin * dy;
        if (dy > 0.0f) { sty = 1;  ply = (int)floorf(q) + 1; }
        else           { sty = -1; ply = (int)ceilf(q)  - 1; }
        ty = ((float)ply - p0y) * invy;
    }
    if (!parz) {
        invz = 1.0f / dz;
        float q = p0z + tmin * dz;
        if (dz > 0.0f) { stz = 1;  plz = (int)floorf(q) + 1; }
        else           { stz = -1; plz = (int)ceilf(q)  - 1; }
        tz = ((float)plz - p0z) * invz;
    }

    float tcur = tmin;
    float acc  = 0.0f;
    int it = 0;
    const int MAXIT = 3 * (NV + 1) + 8;

    while (tcur < tmax && it < MAXIT) {
        ++it;
        float tn = fminf(fminf(tx, ty), fminf(tz, tmax));
        float dt = tn - tcur;
        if (dt > 0.0f) {
            float tm = 0.5f * (tn + tcur);
            int ix = (int)floorf(p0x + tm * dx);
            int iy = (int)floorf(p0y + tm * dy);
            int iz = (int)floorf(p0z + tm * dz);
            if (((unsigned)ix < (unsigned)NV) &
                ((unsigned)iy < (unsigned)NV) &
                ((unsigned)iz < (unsigned)NV)) {
                acc += dt * vol[((ix * NV) + iy) * NV + iz];
            }
        }
        if (tx <= tn) { plx += stx; tx = ((float)plx - p0x) * invx; }
        if (ty <= tn) { ply += sty; ty = ((float)ply - p0y) * invy; }
        if (tz <= tn) { plz += stz; tz = ((float)plz - p0z) * invz; }
        tcur = fmaxf(tcur, tn);
    }

    out[r] = acc * ray_len;
}

extern "C" void kernel_launch(void* const* d_in, const int* in_sizes, int n_in,
                              void* d_out, int out_size, void* d_ws, size_t ws_size,
                              hipStream_t stream) {
    const float* vol  = (const float*)d_in[0];
    const float* M    = (const float*)d_in[1];
    const float* bvec = (const float*)d_in[2];
    const float* src  = (const float*)d_in[3];
    const float* dst  = (const float*)d_in[4];
    float* out = (float*)d_out;

    int n_ray = in_sizes[3] / 3;
    dim3 block(256);
    dim3 grid((n_ray + block.x - 1) / block.x);
    hipLaunchKernelGGL(siddon_fwd_kernel, grid, block, 0, stream,
                       vol, M, bvec, src, dst, out, n_ray);
}

// Round 2
// 26.346 us; speedup vs baseline: 2.2515x; 2.2515x over previous
//
#include <hip/hip_runtime.h>
#include <math.h>

// Siddon exact forward projector, incremental traversal, 8 lanes per ray.
// Each lane traverses a parametric sub-range [ta,tb) of the ray; sub-range
// splits are exact (within a Siddon segment the ray is in one voxel, so
// sub-midpoints floor identically and dt*val contributions sum exactly).

constexpr int   NV    = 128;
constexpr float EPS_F = 1e-12f;
constexpr float BIG_F = 1e9f;
constexpr int   SPLIT = 8;       // lanes per ray (must divide 64)

__global__ __launch_bounds__(256)
void siddon_fwd_kernel(const float* __restrict__ vol,
                       const float* __restrict__ Mptr,
                       const float* __restrict__ bptr,
                       const float* __restrict__ src,
                       const float* __restrict__ dst,
                       float* __restrict__ out,
                       int n_ray)
{
    int gid = blockIdx.x * blockDim.x + threadIdx.x;
    int r   = gid / SPLIT;
    int sub = gid % SPLIT;
    if (r >= n_ray) return;

    // ---- uniform: M inverse via adjugate ----
    float m00 = Mptr[0], m01 = Mptr[1], m02 = Mptr[2];
    float m10 = Mptr[3], m11 = Mptr[4], m12 = Mptr[5];
    float m20 = Mptr[6], m21 = Mptr[7], m22 = Mptr[8];
    float det = m00*(m11*m22 - m12*m21) - m01*(m10*m22 - m12*m20)
              + m02*(m10*m21 - m11*m20);
    float idet = 1.0f / det;
    float i00 =  (m11*m22 - m12*m21)*idet;
    float i01 = -(m01*m22 - m02*m21)*idet;
    float i02 =  (m01*m12 - m02*m11)*idet;
    float i10 = -(m10*m22 - m12*m20)*idet;
    float i11 =  (m00*m22 - m02*m20)*idet;
    float i12 = -(m00*m12 - m02*m10)*idet;
    float i20 =  (m10*m21 - m11*m20)*idet;
    float i21 = -(m00*m21 - m01*m20)*idet;
    float i22 =  (m00*m11 - m01*m10)*idet;

    float bx = bptr[0], by = bptr[1], bz = bptr[2];

    float sxw = src[3*r+0], syw = src[3*r+1], szw = src[3*r+2];
    float exw = dst[3*r+0], eyw = dst[3*r+1], ezw = dst[3*r+2];

    float wx = exw - sxw, wy = eyw - syw, wz = ezw - szw;
    float ray_len = sqrtf(wx*wx + wy*wy + wz*wz);

    float ux = sxw - bx, uy = syw - by, uz = szw - bz;
    float p0x = i00*ux + i01*uy + i02*uz;
    float p0y = i10*ux + i11*uy + i12*uz;
    float p0z = i20*ux + i21*uy + i22*uz;
    float vx = exw - bx, vy = eyw - by, vz = ezw - bz;
    float p1x = i00*vx + i01*vy + i02*vz;
    float p1y = i10*vx + i11*vy + i12*vz;
    float p1z = i20*vx + i21*vy + i22*vz;

    float dx = p1x - p0x, dy = p1y - p0y, dz = p1z - p0z;

    bool parx = fabsf(dx) < EPS_F;
    bool pary = fabsf(dy) < EPS_F;
    bool parz = fabsf(dz) < EPS_F;

    // ---- slab intersection ----
    float tmin = 0.0f, tmax = 1.0f;
    if (parx) {
        bool inside = (p0x >= 0.0f) && (p0x <= (float)NV);
        tmin = fmaxf(tmin, inside ? 0.0f : BIG_F);
        tmax = fminf(tmax, inside ? 1.0f : -BIG_F);
    } else {
        float t0 = (0.0f - p0x) / dx, t1 = ((float)NV - p0x) / dx;
        tmin = fmaxf(tmin, fminf(t0, t1));
        tmax = fminf(tmax, fmaxf(t0, t1));
    }
    if (pary) {
        bool inside = (p0y >= 0.0f) && (p0y <= (float)NV);
        tmin = fmaxf(tmin, inside ? 0.0f : BIG_F);
        tmax = fminf(tmax, inside ? 1.0f : -BIG_F);
    } else {
        float t0 = (0.0f - p0y) / dy, t1 = ((float)NV - p0y) / dy;
        tmin = fmaxf(tmin, fminf(t0, t1));
        tmax = fminf(tmax, fmaxf(t0, t1));
    }
    if (parz) {
        bool inside = (p0z >= 0.0f) && (p0z <= (float)NV);
        tmin = fmaxf(tmin, inside ? 0.0f : BIG_F);
        tmax = fminf(tmax, inside ? 1.0f : -BIG_F);
    } else {
        float t0 = (0.0f - p0z) / dz, t1 = ((float)NV - p0z) / dz;
        tmin = fmaxf(tmin, fminf(t0, t1));
        tmax = fminf(tmax, fmaxf(t0, t1));
    }

    float acc = 0.0f;

    if (tmax > tmin) {
        // ---- this lane's parametric sub-range ----
        float span = (tmax - tmin) * (1.0f / (float)SPLIT);
        float ta = tmin + (float)sub * span;
        float tb = (sub == SPLIT - 1) ? tmax : (tmin + (float)(sub + 1) * span);

        // ---- incremental traversal init at t = ta ----
        float tx = BIG_F, ty = BIG_F, tz = BIG_F;
        float invx = 0.0f, invy = 0.0f, invz = 0.0f;
        int plx = 0, ply = 0, plz = 0;
        int stx = 0, sty = 0, stz = 0;

        if (!parx) {
            invx = 1.0f / dx;
            float q = p0x + ta * dx;
            if (dx > 0.0f) { stx = 1;  plx = (int)floorf(q) + 1; }
            else           { stx = -1; plx = (int)ceilf(q)  - 1; }
            tx = ((float)plx - p0x) * invx;
        }
        if (!pary) {
            invy = 1.0f / dy;
            float q = p0y + ta * dy;
            if (dy > 0.0f) { sty = 1;  ply = (int)floorf(q) + 1; }
            else           { sty = -1; ply = (int)ceilf(q)  - 1; }
            ty = ((float)ply - p0y) * invy;
        }
        if (!parz) {
            invz = 1.0f / dz;
            float q = p0z + ta * dz;
            if (dz > 0.0f) { stz = 1;  plz = (int)floorf(q) + 1; }
            else           { stz = -1; plz = (int)ceilf(q)  - 1; }
            tz = ((float)plz - p0z) * invz;
        }

        float tcur = ta;
        int it = 0;
        const int MAXIT = 3 * (NV + 1) / SPLIT + 12;

        while (tcur < tb && it < MAXIT) {
            ++it;
            float tn = fminf(fminf(tx, ty), fminf(tz, tb));
            float dt = tn - tcur;
            if (dt > 0.0f) {
                float tm = 0.5f * (tn + tcur);
                int ix = (int)floorf(p0x + tm * dx);
                int iy = (int)floorf(p0y + tm * dy);
                int iz = (int)floorf(p0z + tm * dz);
                if (((unsigned)ix < (unsigned)NV) &
                    ((unsigned)iy < (unsigned)NV) &
                    ((unsigned)iz < (unsigned)NV)) {
                    acc += dt * vol[((ix * NV) + iy) * NV + iz];
                }
            }
            if (tx <= tn) { plx += stx; tx = ((float)plx - p0x) * invx; }
            if (ty <= tn) { ply += sty; ty = ((float)ply - p0y) * invy; }
            if (tz <= tn) { plz += stz; tz = ((float)plz - p0z) * invz; }
            tcur = fmaxf(tcur, tn);
        }
    }

    // ---- reduce across the 8-lane group (aligned within the wave) ----
    acc += __shfl_xor(acc, 1, 64);
    acc += __shfl_xor(acc, 2, 64);
    acc += __shfl_xor(acc, 4, 64);

    if (sub == 0) out[r] = acc * ray_len;
}

extern "C" void kernel_launch(void* const* d_in, const int* in_sizes, int n_in,
                              void* d_out, int out_size, void* d_ws, size_t ws_size,
                              hipStream_t stream) {
    const float* vol  = (const float*)d_in[0];
    const float* M    = (const float*)d_in[1];
    const float* bvec = (const float*)d_in[2];
    const float* src  = (const float*)d_in[3];
    const float* dst  = (const float*)d_in[4];
    float* out = (float*)d_out;

    int n_ray = in_sizes[3] / 3;
    long long total = (long long)n_ray * SPLIT;
    dim3 block(256);
    dim3 grid((unsigned)((total + block.x - 1) / block.x));
    hipLaunchKernelGGL(siddon_fwd_kernel, grid, block, 0, stream,
                       vol, M, bvec, src, dst, out, n_ray);
}

// Round 3
// 18.191 us; speedup vs baseline: 3.2609x; 1.4483x over previous
//
#include <hip/hip_runtime.h>
#include <math.h>

// Siddon exact forward projector — incremental (Amanatides-Woo) traversal.
// 8 lanes per ray (parametric sub-ranges), arranged sub-major in the wave:
// lanes 0..7 = 8 consecutive rays at sub-range 0, lanes 8..15 same rays at
// sub-range 1, etc. Gather addresses within a lane-group are ~consecutive
// (adjacent detector-z rays sample adjacent iz at equal t) -> L2-friendly.
// Reduction over sub = shfl_xor over lane bits 3,4,5.

constexpr int      NV    = 128;
constexpr int      NVSQ  = NV * NV;
constexpr unsigned NV3   = (unsigned)NV * NV * NV;
constexpr float    EPS_F = 1e-12f;
constexpr float    BIG_F = 1e9f;
constexpr int      SPLIT = 8;   // sub-ranges per ray
constexpr int      RPW   = 8;   // rays per wave

__global__ __launch_bounds__(256)
void siddon_fwd_kernel(const float* __restrict__ vol,
                       const float* __restrict__ Mptr,
                       const float* __restrict__ bptr,
                       const float* __restrict__ src,
                       const float* __restrict__ dst,
                       float* __restrict__ out,
                       int n_ray)
{
    int gid  = blockIdx.x * blockDim.x + threadIdx.x;
    int lane = threadIdx.x & 63;
    int wave = gid >> 6;
    int r    = wave * RPW + (lane & (RPW - 1));
    int sub  = lane >> 3;
    bool active = (r < n_ray);
    int rc = active ? r : (n_ray - 1);   // clamped for loads

    // ---- uniform: M inverse via adjugate ----
    float m00 = Mptr[0], m01 = Mptr[1], m02 = Mptr[2];
    float m10 = Mptr[3], m11 = Mptr[4], m12 = Mptr[5];
    float m20 = Mptr[6], m21 = Mptr[7], m22 = Mptr[8];
    float det = m00*(m11*m22 - m12*m21) - m01*(m10*m22 - m12*m20)
              + m02*(m10*m21 - m11*m20);
    float idet = 1.0f / det;
    float i00 =  (m11*m22 - m12*m21)*idet;
    float i01 = -(m01*m22 - m02*m21)*idet;
    float i02 =  (m01*m12 - m02*m11)*idet;
    float i10 = -(m10*m22 - m12*m20)*idet;
    float i11 =  (m00*m22 - m02*m20)*idet;
    float i12 = -(m00*m12 - m02*m10)*idet;
    float i20 =  (m10*m21 - m11*m20)*idet;
    float i21 = -(m00*m21 - m01*m20)*idet;
    float i22 =  (m00*m11 - m01*m10)*idet;

    float bx = bptr[0], by = bptr[1], bz = bptr[2];

    float sxw = src[3*rc+0], syw = src[3*rc+1], szw = src[3*rc+2];
    float exw = dst[3*rc+0], eyw = dst[3*rc+1], ezw = dst[3*rc+2];

    float wxw = exw - sxw, wyw = eyw - syw, wzw = ezw - szw;
    float ray_len = sqrtf(wxw*wxw + wyw*wyw + wzw*wzw);

    float ux = sxw - bx, uy = syw - by, uz = szw - bz;
    float p0x = i00*ux + i01*uy + i02*uz;
    float p0y = i10*ux + i11*uy + i12*uz;
    float p0z = i20*ux + i21*uy + i22*uz;
    float vx = exw - bx, vy = eyw - by, vz = ezw - bz;
    float p1x = i00*vx + i01*vy + i02*vz;
    float p1y = i10*vx + i11*vy + i12*vz;
    float p1z = i20*vx + i21*vy + i22*vz;

    float dx = p1x - p0x, dy = p1y - p0y, dz = p1z - p0z;

    bool parx = fabsf(dx) < EPS_F;
    bool pary = fabsf(dy) < EPS_F;
    bool parz = fabsf(dz) < EPS_F;

    // ---- slab intersection ----
    float tmin = 0.0f, tmax = 1.0f;
    if (parx) {
        bool inside = (p0x >= 0.0f) && (p0x <= (float)NV);
        tmin = fmaxf(tmin, inside ? 0.0f : BIG_F);
        tmax = fminf(tmax, inside ? 1.0f : -BIG_F);
    } else {
        float t0 = (0.0f - p0x) / dx, t1 = ((float)NV - p0x) / dx;
        tmin = fmaxf(tmin, fminf(t0, t1));
        tmax = fminf(tmax, fmaxf(t0, t1));
    }
    if (pary) {
        bool inside = (p0y >= 0.0f) && (p0y <= (float)NV);
        tmin = fmaxf(tmin, inside ? 0.0f : BIG_F);
        tmax = fminf(tmax, inside ? 1.0f : -BIG_F);
    } else {
        float t0 = (0.0f - p0y) / dy, t1 = ((float)NV - p0y) / dy;
        tmin = fmaxf(tmin, fminf(t0, t1));
        tmax = fminf(tmax, fmaxf(t0, t1));
    }
    if (parz) {
        bool inside = (p0z >= 0.0f) && (p0z <= (float)NV);
        tmin = fmaxf(tmin, inside ? 0.0f : BIG_F);
        tmax = fminf(tmax, inside ? 1.0f : -BIG_F);
    } else {
        float t0 = (0.0f - p0z) / dz, t1 = ((float)NV - p0z) / dz;
        tmin = fmaxf(tmin, fminf(t0, t1));
        tmax = fminf(tmax, fmaxf(t0, t1));
    }

    float acc = 0.0f;

    if (active && (tmax > tmin)) {
        float span = (tmax - tmin) * (1.0f / (float)SPLIT);
        float ta = tmin + (float)sub * span;
        float tb = (sub == SPLIT - 1) ? tmax : (tmin + (float)(sub + 1) * span);

        // ---- DDA init at t = ta: next-crossing t, per-axis t-step, voxel idx ----
        float tx = BIG_F, ty = BIG_F, tz = BIG_F;
        float adx = 0.0f, ady = 0.0f, adz = 0.0f;
        int ix, iy, iz;
        int ox = 0, oy = 0, oz = 0;

        if (!parx) {
            float invx = 1.0f / dx;
            adx = fabsf(invx);
            float q = p0x + ta * dx;
            int pl;
            if (dx > 0.0f) { pl = (int)floorf(q) + 1; ix = pl - 1; ox =  NVSQ; }
            else           { pl = (int)ceilf(q)  - 1; ix = pl;     ox = -NVSQ; }
            tx = ((float)pl - p0x) * invx;
        } else {
            ix = (int)floorf(p0x);
        }
        if (!pary) {
            float invy = 1.0f / dy;
            ady = fabsf(invy);
            float q = p0y + ta * dy;
            int pl;
            if (dy > 0.0f) { pl = (int)floorf(q) + 1; iy = pl - 1; oy =  NV; }
            else           { pl = (int)ceilf(q)  - 1; iy = pl;     oy = -NV; }
            ty = ((float)pl - p0y) * invy;
        } else {
            iy = (int)floorf(p0y);
        }
        if (!parz) {
            float invz = 1.0f / dz;
            adz = fabsf(invz);
            float q = p0z + ta * dz;
            int pl;
            if (dz > 0.0f) { pl = (int)floorf(q) + 1; iz = pl - 1; oz =  1; }
            else           { pl = (int)ceilf(q)  - 1; iz = pl;     oz = -1; }
            tz = ((float)pl - p0z) * invz;
        } else {
            iz = (int)floorf(p0z);
        }

        int flat = ix * NVSQ + iy * NV + iz;

        float tcur = ta;
        int it = 0;
        const int MAXIT = 3 * (NV + 1) / SPLIT + 32;

        while (tcur < tb && it < MAXIT) {
            ++it;
            float tn = fminf(fminf(tx, ty), fminf(tz, tb));
            float dt = tn - tcur;

            unsigned uf = (unsigned)flat;
            unsigned cl = uf < NV3 ? uf : (NV3 - 1u);
            float v = vol[cl];
            acc = fmaf(dt, (uf < NV3) ? v : 0.0f, acc);

            bool sx = (tx <= tn), sy = (ty <= tn), sz = (tz <= tn);
            tx   += sx ? adx : 0.0f;
            flat += sx ? ox  : 0;
            ty   += sy ? ady : 0.0f;
            flat += sy ? oy  : 0;
            tz   += sz ? adz : 0.0f;
            flat += sz ? oz  : 0;
            tcur = tn;
        }
    }

    // ---- reduce over the sub dimension (lane bits 3,4,5) ----
    acc += __shfl_xor(acc, 8,  64);
    acc += __shfl_xor(acc, 16, 64);
    acc += __shfl_xor(acc, 32, 64);

    if (active && sub == 0) out[r] = acc * ray_len;
}

extern "C" void kernel_launch(void* const* d_in, const int* in_sizes, int n_in,
                              void* d_out, int out_size, void* d_ws, size_t ws_size,
                              hipStream_t stream) {
    const float* vol  = (const float*)d_in[0];
    const float* M    = (const float*)d_in[1];
    const float* bvec = (const float*)d_in[2];
    const float* src  = (const float*)d_in[3];
    const float* dst  = (const float*)d_in[4];
    float* out = (float*)d_out;

    int n_ray = in_sizes[3] / 3;
    long long waves = (n_ray + RPW - 1) / RPW;
    long long total = waves * 64;
    dim3 block(256);
    dim3 grid((unsigned)((total + block.x - 1) / block.x));
    hipLaunchKernelGGL(siddon_fwd_kernel, grid, block, 0, stream,
                       vol, M, bvec, src, dst, out, n_ray);
}

// Round 4
// 17.581 us; speedup vs baseline: 3.3740x; 1.0347x over previous
//
#include <hip/hip_runtime.h>
#include <math.h>

// Siddon exact forward projector — incremental (Amanatides-Woo) traversal.
// Layout: one block = 512 threads = 8 waves = one group of 64 CONSECUTIVE
// rays x 8 parametric sub-ranges. All rays in a group share detector-u, so
// at equal t they share (ix,iy) and span ~17-33 consecutive iz -> a wave's
// 64 gathers hit only 2-4 cachelines (minimal L2 traffic). Per-ray partial
// sums are combined through a conflict-free LDS [8][64] reduction.

constexpr int      NV    = 128;
constexpr int      NVSQ  = NV * NV;
constexpr unsigned NV3   = (unsigned)NV * NV * NV;
constexpr float    EPS_F = 1e-12f;
constexpr float    BIG_F = 1e9f;
constexpr int      SPLIT = 8;    // sub-ranges per ray = waves per block
constexpr int      RPB   = 64;   // rays per block (= lanes per wave)

__global__ __launch_bounds__(512)
void siddon_fwd_kernel(const float* __restrict__ vol,
                       const float* __restrict__ Mptr,
                       const float* __restrict__ bptr,
                       const float* __restrict__ src,
                       const float* __restrict__ dst,
                       float* __restrict__ out,
                       int n_ray)
{
    int lane = threadIdx.x & 63;
    int sub  = threadIdx.x >> 6;            // 0..7, one sub-range per wave
    int r    = blockIdx.x * RPB + lane;
    bool active = (r < n_ray);
    int rc = active ? r : (n_ray - 1);      // clamped for loads

    // ---- uniform: M inverse via adjugate ----
    float m00 = Mptr[0], m01 = Mptr[1], m02 = Mptr[2];
    float m10 = Mptr[3], m11 = Mptr[4], m12 = Mptr[5];
    float m20 = Mptr[6], m21 = Mptr[7], m22 = Mptr[8];
    float det = m00*(m11*m22 - m12*m21) - m01*(m10*m22 - m12*m20)
              + m02*(m10*m21 - m11*m20);
    float idet = 1.0f / det;
    float i00 =  (m11*m22 - m12*m21)*idet;
    float i01 = -(m01*m22 - m02*m21)*idet;
    float i02 =  (m01*m12 - m02*m11)*idet;
    float i10 = -(m10*m22 - m12*m20)*idet;
    float i11 =  (m00*m22 - m02*m20)*idet;
    float i12 = -(m00*m12 - m02*m10)*idet;
    float i20 =  (m10*m21 - m11*m20)*idet;
    float i21 = -(m00*m21 - m01*m20)*idet;
    float i22 =  (m00*m11 - m01*m10)*idet;

    float bx = bptr[0], by = bptr[1], bz = bptr[2];

    float sxw = src[3*rc+0], syw = src[3*rc+1], szw = src[3*rc+2];
    float exw = dst[3*rc+0], eyw = dst[3*rc+1], ezw = dst[3*rc+2];

    float wxw = exw - sxw, wyw = eyw - syw, wzw = ezw - szw;
    float ray_len = sqrtf(wxw*wxw + wyw*wyw + wzw*wzw);

    float ux = sxw - bx, uy = syw - by, uz = szw - bz;
    float p0x = i00*ux + i01*uy + i02*uz;
    float p0y = i10*ux + i11*uy + i12*uz;
    float p0z = i20*ux + i21*uy + i22*uz;
    float vx = exw - bx, vy = eyw - by, vz = ezw - bz;
    float p1x = i00*vx + i01*vy + i02*vz;
    float p1y = i10*vx + i11*vy + i12*vz;
    float p1z = i20*vx + i21*vy + i22*vz;

    float dx = p1x - p0x, dy = p1y - p0y, dz = p1z - p0z;

    bool parx = fabsf(dx) < EPS_F;
    bool pary = fabsf(dy) < EPS_F;
    bool parz = fabsf(dz) < EPS_F;

    // ---- slab intersection ----
    float tmin = 0.0f, tmax = 1.0f;
    if (parx) {
        bool inside = (p0x >= 0.0f) && (p0x <= (float)NV);
        tmin = fmaxf(tmin, inside ? 0.0f : BIG_F);
        tmax = fminf(tmax, inside ? 1.0f : -BIG_F);
    } else {
        float t0 = (0.0f - p0x) / dx, t1 = ((float)NV - p0x) / dx;
        tmin = fmaxf(tmin, fminf(t0, t1));
        tmax = fminf(tmax, fmaxf(t0, t1));
    }
    if (pary) {
        bool inside = (p0y >= 0.0f) && (p0y <= (float)NV);
        tmin = fmaxf(tmin, inside ? 0.0f : BIG_F);
        tmax = fminf(tmax, inside ? 1.0f : -BIG_F);
    } else {
        float t0 = (0.0f - p0y) / dy, t1 = ((float)NV - p0y) / dy;
        tmin = fmaxf(tmin, fminf(t0, t1));
        tmax = fminf(tmax, fmaxf(t0, t1));
    }
    if (parz) {
        bool inside = (p0z >= 0.0f) && (p0z <= (float)NV);
        tmin = fmaxf(tmin, inside ? 0.0f : BIG_F);
        tmax = fminf(tmax, inside ? 1.0f : -BIG_F);
    } else {
        float t0 = (0.0f - p0z) / dz, t1 = ((float)NV - p0z) / dz;
        tmin = fmaxf(tmin, fminf(t0, t1));
        tmax = fminf(tmax, fmaxf(t0, t1));
    }

    float acc = 0.0f;

    if (active && (tmax > tmin)) {
        float span = (tmax - tmin) * (1.0f / (float)SPLIT);
        float ta = tmin + (float)sub * span;
        float tb = (sub == SPLIT - 1) ? tmax : (tmin + (float)(sub + 1) * span);

        // ---- DDA init at t = ta ----
        float tx = BIG_F, ty = BIG_F, tz = BIG_F;
        float adx = 0.0f, ady = 0.0f, adz = 0.0f;
        int ix, iy, iz;
        int ox = 0, oy = 0, oz = 0;

        if (!parx) {
            float invx = 1.0f / dx;
            adx = fabsf(invx);
            float q = p0x + ta * dx;
            int pl;
            if (dx > 0.0f) { pl = (int)floorf(q) + 1; ix = pl - 1; ox =  NVSQ; }
            else           { pl = (int)ceilf(q)  - 1; ix = pl;     ox = -NVSQ; }
            tx = ((float)pl - p0x) * invx;
        } else {
            ix = (int)floorf(p0x);
        }
        if (!pary) {
            float invy = 1.0f / dy;
            ady = fabsf(invy);
            float q = p0y + ta * dy;
            int pl;
            if (dy > 0.0f) { pl = (int)floorf(q) + 1; iy = pl - 1; oy =  NV; }
            else           { pl = (int)ceilf(q)  - 1; iy = pl;     oy = -NV; }
            ty = ((float)pl - p0y) * invy;
        } else {
            iy = (int)floorf(p0y);
        }
        if (!parz) {
            float invz = 1.0f / dz;
            adz = fabsf(invz);
            float q = p0z + ta * dz;
            int pl;
            if (dz > 0.0f) { pl = (int)floorf(q) + 1; iz = pl - 1; oz =  1; }
            else           { pl = (int)ceilf(q)  - 1; iz = pl;     oz = -1; }
            tz = ((float)pl - p0z) * invz;
        } else {
            iz = (int)floorf(p0z);
        }

        int flat = ix * NVSQ + iy * NV + iz;

        float tcur = ta;
        int it = 0;
        const int MAXIT = 3 * (NV + 1) / SPLIT + 32;

        while (tcur < tb && it < MAXIT) {
            ++it;
            float tn = fminf(fminf(tx, ty), fminf(tz, tb));
            float dt = tn - tcur;

            unsigned uf = (unsigned)flat;
            unsigned cl = uf < NV3 ? uf : (NV3 - 1u);
            float v = vol[cl];
            acc = fmaf(dt, (uf < NV3) ? v : 0.0f, acc);

            bool sx = (tx <= tn), sy = (ty <= tn), sz = (tz <= tn);
            tx   += sx ? adx : 0.0f;
            flat += sx ? ox  : 0;
            ty   += sy ? ady : 0.0f;
            flat += sy ? oy  : 0;
            tz   += sz ? adz : 0.0f;
            flat += sz ? oz  : 0;
            tcur = tn;
        }
    }

    // ---- block reduction over the 8 sub-ranges: LDS [8][64], conflict-free ----
    __shared__ float part[SPLIT][RPB];
    part[sub][lane] = acc;
    __syncthreads();

    if (threadIdx.x < RPB && active) {
        float s = 0.0f;
        #pragma unroll
        for (int w = 0; w < SPLIT; ++w) s += part[w][threadIdx.x];
        out[r] = s * ray_len;
    }
}

extern "C" void kernel_launch(void* const* d_in, const int* in_sizes, int n_in,
                              void* d_out, int out_size, void* d_ws, size_t ws_size,
                              hipStream_t stream) {
    const float* vol  = (const float*)d_in[0];
    const float* M    = (const float*)d_in[1];
    const float* bvec = (const float*)d_in[2];
    const float* src  = (const float*)d_in[3];
    const float* dst  = (const float*)d_in[4];
    float* out = (float*)d_out;

    int n_ray = in_sizes[3] / 3;
    int nblk = (n_ray + RPB - 1) / RPB;
    dim3 block(512);
    dim3 grid((unsigned)nblk);
    hipLaunchKernelGGL(siddon_fwd_kernel, grid, block, 0, stream,
                       vol, M, bvec, src, dst, out, n_ray);
}